// Round 9
// baseline (241.698 us; speedup 1.0000x reference)
//
#include <hip/hip_runtime.h>
#include <hip/hip_bf16.h>

#define KE_F   332.0636f
#define MAX_M  1024   // padded molecule count (harness M = 1000)
#define BLK    256
#define NBLK   2048   // best measured grid
#define WCHUNK 256    // edges per wave-iteration (4 per lane)

typedef int   ivec2 __attribute__((ext_vector_type(2)));
typedef int   ivec4 __attribute__((ext_vector_type(4)));
typedef float fvec4 __attribute__((ext_vector_type(4)));

__device__ __forceinline__ float softplusf(float x) {
    return logf(1.0f + expf(x));
}

// Compile-time fence: no instruction emitted; blocks the scheduler from
// moving LDS/VMEM ops across it (wave-synchronous LDS exchange idiom).
__device__ __forceinline__ void wave_fence() {
    __builtin_amdgcn_wave_barrier();
    asm volatile("" ::: "memory");
}

// One block: prefix-scan num_atoms -> mol_starts[M+1]; derived constants into
// params: [0..3]=c_k/sum(c), [4..7]=exponents_k/d, [16..111]=Z^zexp table;
// also zeroes out[0..M) (harness re-poisons d_out to 0xAA each launch).
__global__ void scan_params_kernel(const int* __restrict__ num_atoms, int M,
                                   const float* __restrict__ d_inv,
                                   const float* __restrict__ z_exp_inv,
                                   const float* __restrict__ c_inv,
                                   const float* __restrict__ exp_inv,
                                   int* __restrict__ mol_starts,
                                   float* __restrict__ params,
                                   float* __restrict__ out) {
    __shared__ int buf[MAX_M];
    int t = threadIdx.x;
    buf[t] = (t < M) ? num_atoms[t] : 0;
    __syncthreads();
    for (int off = 1; off < MAX_M; off <<= 1) {   // Hillis-Steele inclusive scan
        int x = (t >= off) ? buf[t - off] : 0;
        __syncthreads();
        buf[t] += x;
        __syncthreads();
    }
    if (t == 0) mol_starts[0] = 0;
    if (t < M) mol_starts[t + 1] = buf[t];
    if (t == 0) {
        float dd = softplusf(d_inv[0]);
        float c0 = softplusf(c_inv[0]), c1 = softplusf(c_inv[1]);
        float c2 = softplusf(c_inv[2]), c3 = softplusf(c_inv[3]);
        float e0 = softplusf(exp_inv[0]), e1 = softplusf(exp_inv[1]);
        float e2 = softplusf(exp_inv[2]), e3 = softplusf(exp_inv[3]);
        float ic = 1.0f / (c0 + c1 + c2 + c3);
        float id = 1.0f / dd;
        params[0] = c0 * ic; params[1] = c1 * ic; params[2] = c2 * ic; params[3] = c3 * ic;
        params[4] = e0 * id; params[5] = e1 * id; params[6] = e2 * id; params[7] = e3 * id;
    }
    if (t < 96) {                                  // z in [1,94): table of Z^zexp
        float zexp = softplusf(z_exp_inv[0]);
        params[16 + t] = __powf((float)t, zexp);
    }
    for (int k = t; k < M; k += MAX_M) out[k] = 0.0f;
}

// Per-atom packing: pack[a] = (x, y, z, encode(mol, Z)) where
// encode = float((mol << 7) | Z)  (exact: < 2^17). mol via binary search on
// mol_starts (clamps to M-1, matching jnp.repeat total_repeat_length pad).
__global__ void pack_kernel(const float* __restrict__ xyz,
                            const int* __restrict__ z,
                            const int* __restrict__ mol_starts, int M, int N,
                            float4* __restrict__ pack) {
    int a = blockIdx.x * blockDim.x + threadIdx.x;
    if (a >= N) return;
    int lo = 0, hi = M;
    while (hi - lo > 1) {
        int mid = (lo + hi) >> 1;
        if (mol_starts[mid] <= a) lo = mid; else hi = mid;
    }
    pack[a] = make_float4(xyz[3 * a + 0], xyz[3 * a + 1], xyz[3 * a + 2],
                          (float)((lo << 7) | z[a]));
}

// R6 structure (verified best, 74.5us, absmax 0.0) with ONE change:
// __launch_bounds__(BLK, 3). R8's VGPR_Count=36 proves the allocator
// serialized the 8-gather batch (8 in-flight float4 results alone need
// 32 VGPRs) — without a min-waves hint hipcc targets max occupancy and
// minimizes registers. (BLK,3) raises the budget to ~170 VGPR (12
// waves/CU), the TLP regime R2 measured as nearly free (-5%), letting
// the allocator keep the whole gather batch in flight.
// Branch A (budget-driven): VGPR 60-130, nr_main 62-70us.
// Branch B (scheduler-driven): VGPR <=48, dur unchanged -> ILP lane is
// triple-falsified and the line-service ceiling gets declared.
__global__ __launch_bounds__(BLK, 3) void nr_main_kernel(
    const int* __restrict__ nbrs, const float* __restrict__ offsets,
    const float4* __restrict__ pack,
    const float* __restrict__ params, float* __restrict__ out, int E, int M) {
    __shared__ float sm[MAX_M];
    __shared__ float zp[96];
    __shared__ float sof[4][WCHUNK * 3];   // 12 KB: per-wave offset bounce
    for (int t = threadIdx.x; t < MAX_M; t += BLK) sm[t] = 0.0f;
    if (threadIdx.x < 96) zp[threadIdx.x] = params[16 + threadIdx.x];
    __syncthreads();

    const float4 kk = *(const float4*)(params + 0);   // phi coefficients
    const float4 gg = *(const float4*)(params + 4);   // exponent scales (/d folded)

    const int lane = threadIdx.x & 63;
    float* myof = sof[threadIdx.x >> 6];              // this wave's private region

    const int nchunks = E / WCHUNK;
    const int gw = (blockIdx.x * BLK + threadIdx.x) >> 6;   // global wave id
    const int nw = (gridDim.x * BLK) >> 6;                  // total waves

    const ivec2* nbp = (const ivec2*)nbrs;
    const fvec4* of4 = (const fvec4*)offsets;

    for (int c = gw; c < nchunks; c += nw) {
        const size_t eb = (size_t)c * WCHUNK;
        // nbrs: per-lane int2, perfectly coalesced (512B/instr).
        ivec2 nb[4];
#pragma unroll
        for (int h = 0; h < 4; ++h)
            nb[h] = __builtin_nontemporal_load(nbp + eb + 64 * h + lane);
        // offsets: 3 coalesced float4 instrs (1024B each), for LDS bounce.
        const fvec4* ofb = of4 + (size_t)c * ((WCHUNK * 3) / 4);
        const fvec4 F0 = __builtin_nontemporal_load(ofb + lane);
        const fvec4 F1 = __builtin_nontemporal_load(ofb + 64 + lane);
        const fvec4 F2 = __builtin_nontemporal_load(ofb + 128 + lane);

        // Issue ALL 8 gathers batched, branch-free (masked lanes -> line 0),
        // before the LDS-write section (no vmcnt dependence on F0-F2).
        bool   m[4];
        float4 pi[4], pj[4];
#pragma unroll
        for (int h = 0; h < 4; ++h) {
            const int iv = nb[h].x, jv = nb[h].y;
            m[h] = jv > iv;
            pi[h] = pack[m[h] ? iv : 0];
            pj[h] = pack[m[h] ? jv : 0];
        }

        wave_fence();   // WAR: prev iteration's LDS reads complete first
        *(fvec4*)&myof[4 * lane]       = F0;   // conflict-free b128 writes;
        *(fvec4*)&myof[4 * lane + 256] = F1;   // myof[f] = offsets[768c+f]
        *(fvec4*)&myof[4 * lane + 512] = F2;
        wave_fence();   // RAW: reads below must not hoist above the writes

#pragma unroll
        for (int h = 0; h < 4; ++h) {
            // lane's edge h = eb + 64h + lane; its floats at 192h+3*lane.
            const float oxv = myof[192 * h + 3 * lane + 0];
            const float oyv = myof[192 * h + 3 * lane + 1];
            const float ozv = myof[192 * h + 3 * lane + 2];
            const float dx = pi[h].x - pj[h].x - oxv;
            const float dy = pi[h].y - pj[h].y - oyv;
            const float dz = pi[h].z - pj[h].z - ozv;
            const float r2 = fmaf(dx, dx, fmaf(dy, dy, dz * dz)) + 3e-15f;
            const bool ok = m[h] && (r2 < 25.0f);
            const int  wi = (int)pi[h].w;
            const int  wj = (int)pj[h].w;
            const float zi = (float)(wi & 127);
            const float zj = (float)(wj & 127);
            const float inv_r = rsqrtf(r2);
            const float r = r2 * inv_r;
            const float S = zp[wi & 127] + zp[wj & 127];
            const float rs = r * S;
            const float phi = kk.x * __expf(-gg.x * rs) + kk.y * __expf(-gg.y * rs) +
                              kk.z * __expf(-gg.z * rs) + kk.w * __expf(-gg.w * rs);
            const float fc = __expf(-__fdividef(r2, 25.0f - r2));
            const float val = KE_F * zi * zj * inv_r * phi * fc;
            if (ok) atomicAdd(&sm[wi >> 7], val);   // inf/nan of masked lanes discarded
        }
    }

    // Tail edges [nchunks*WCHUNK, E) — scalar path (empty in harness).
    const int stride = gridDim.x * BLK;
    for (int e = nchunks * WCHUNK + blockIdx.x * BLK + threadIdx.x; e < E; e += stride) {
        const int i = nbrs[2 * e], j = nbrs[2 * e + 1];
        if (j <= i) continue;
        const float oxs = offsets[3 * e], oys = offsets[3 * e + 1], ozs = offsets[3 * e + 2];
        const float4 pis = pack[i], pjs = pack[j];
        const float dx = pis.x - pjs.x - oxs;
        const float dy = pis.y - pjs.y - oys;
        const float dz = pis.z - pjs.z - ozs;
        const float r2 = fmaf(dx, dx, fmaf(dy, dy, dz * dz)) + 3e-15f;
        if (r2 >= 25.0f) continue;
        const int  wi = (int)pis.w;
        const int  wj = (int)pjs.w;
        const float inv_r = rsqrtf(r2);
        const float r = r2 * inv_r;
        const float S = zp[wi & 127] + zp[wj & 127];
        const float rs = r * S;
        const float phi = kk.x * __expf(-gg.x * rs) + kk.y * __expf(-gg.y * rs) +
                          kk.z * __expf(-gg.z * rs) + kk.w * __expf(-gg.w * rs);
        const float fc = __expf(-__fdividef(r2, 25.0f - r2));
        atomicAdd(&sm[wi >> 7],
                  KE_F * (float)(wi & 127) * (float)(wj & 127) * inv_r * phi * fc);
    }

    __syncthreads();
    // Sparse flush: ~35% of slots nonzero per block -> ~0.7M global atomics total.
    for (int t = threadIdx.x; t < M; t += BLK) {
        const float v = sm[t];
        if (v != 0.0f) atomicAdd(&out[t], v);
    }
}

extern "C" void kernel_launch(void* const* d_in, const int* in_sizes, int n_in,
                              void* d_out, int out_size, void* d_ws, size_t ws_size,
                              hipStream_t stream) {
    const float* xyz       = (const float*)d_in[0];
    const int*   z         = (const int*)d_in[1];
    const int*   nbrs      = (const int*)d_in[2];
    const int*   num_atoms = (const int*)d_in[3];
    const float* offsets   = (const float*)d_in[4];
    const float* d_inv     = (const float*)d_in[5];
    const float* z_exp_inv = (const float*)d_in[6];
    const float* c_inv     = (const float*)d_in[7];
    const float* exp_inv   = (const float*)d_in[8];
    float* out = (float*)d_out;

    const int N = in_sizes[0] / 3;
    const int E = in_sizes[2] / 2;
    const int M = in_sizes[3];

    // Workspace layout (16B-aligned regions):
    //   [0, 4096)            : mol_starts (M+1 ints)
    //   [4096, 8192)         : params (112 floats used)
    //   [8192, 8192+16N)     : pack (N float4; w = (mol<<7)|Z encoded)
    char* w = (char*)d_ws;
    int*    mol_starts = (int*)w;
    float*  params     = (float*)(w + 4096);
    float4* pack       = (float4*)(w + 8192);

    scan_params_kernel<<<1, MAX_M, 0, stream>>>(num_atoms, M, d_inv, z_exp_inv,
                                                c_inv, exp_inv, mol_starts,
                                                params, out);
    pack_kernel<<<(N + BLK - 1) / BLK, BLK, 0, stream>>>(xyz, z, mol_starts, M, N,
                                                         pack);
    nr_main_kernel<<<NBLK, BLK, 0, stream>>>(nbrs, offsets, pack,
                                             params, out, E, M);
}